// Round 5
// baseline (382.410 us; speedup 1.0000x reference)
//
#include <hip/hip_runtime.h>
#include <hip/hip_fp16.h>

#define NN 50000
#define EE 800000
#define BB 512
#define DIN 128
#define HH 64
#define DOUT 32
#define BN_EPS 1e-5f
#define SCAN_BLOCKS 196   // ceil(50000/256)
#define GATHER_BLOCKS 2048

// ---------------- proj: Qh = half(X @ W)  (no bias; bias folded into gather) ----------------
template <int CIN>
__global__ __launch_bounds__(256) void proj_kernel(const float* __restrict__ X,
                                                   const float* __restrict__ W,  // [CIN][64]
                                                   __half2* __restrict__ Qh)     // [N+1][32]
{
    __shared__ float sW[CIN * 64];
    __shared__ float sX[16 * CIN];
    const int tid = threadIdx.x;
    const int row0 = blockIdx.x * 16;

    for (int i = tid; i < CIN * 16; i += 256)
        ((float4*)sW)[i] = ((const float4*)W)[i];
    const float* Xb = X + (size_t)row0 * CIN;
    for (int i = tid; i < 16 * CIN / 4; i += 256)
        ((float4*)sX)[i] = ((const float4*)Xb)[i];
    __syncthreads();

    const int col2 = tid & 31;   // column pair
    const int rg   = tid >> 5;   // 0..7 -> rows rg*2, rg*2+1
    float2 acc0 = {0.f, 0.f};
    float2 acc1 = {0.f, 0.f};
    const float* x0p = &sX[(rg * 2 + 0) * CIN];
    const float* x1p = &sX[(rg * 2 + 1) * CIN];
#pragma unroll 4
    for (int k = 0; k < CIN; ++k) {
        const float2 w = *(const float2*)&sW[k * 64 + col2 * 2];
        const float x0 = x0p[k];
        const float x1 = x1p[k];
        acc0.x = fmaf(x0, w.x, acc0.x);
        acc0.y = fmaf(x0, w.y, acc0.y);
        acc1.x = fmaf(x1, w.x, acc1.x);
        acc1.y = fmaf(x1, w.y, acc1.y);
    }
    const int r0 = row0 + rg * 2;
    Qh[(size_t)(r0 + 0) * 32 + col2] = __floats2half2_rn(acc0.x, acc0.y);
    Qh[(size_t)(r0 + 1) * 32 + col2] = __floats2half2_rn(acc1.x, acc1.y);
}

// ---------------- CSR build ----------------
__global__ __launch_bounds__(256) void hist_rank_kernel(const int* __restrict__ dst,
                                                        int* __restrict__ deg,
                                                        unsigned short* __restrict__ rank)
{
    const int e = blockIdx.x * 256 + threadIdx.x;  // exactly E threads
    rank[e] = (unsigned short)atomicAdd(&deg[dst[e]], 1);
}

__global__ __launch_bounds__(256) void scanA_kernel(const int* __restrict__ deg,
                                                    int* __restrict__ offs,
                                                    int* __restrict__ blockSums)
{
    __shared__ int s[256];
    const int t = threadIdx.x;
    const int i = blockIdx.x * 256 + t;
    const int v = (i < NN) ? deg[i] : 0;
    s[t] = v;
    __syncthreads();
    for (int off = 1; off < 256; off <<= 1) {
        const int a = (t >= off) ? s[t - off] : 0;
        __syncthreads();
        s[t] += a;
        __syncthreads();
    }
    if (i < NN) offs[i] = s[t] - v;  // exclusive intra-block
    if (t == 255) blockSums[blockIdx.x] = s[255];
}

__global__ __launch_bounds__(256) void scanB_kernel(const int* __restrict__ blockSums,
                                                    int* __restrict__ blockOff)
{
    __shared__ int s[256];
    const int t = threadIdx.x;
    const int v = (t < SCAN_BLOCKS) ? blockSums[t] : 0;
    s[t] = v;
    __syncthreads();
    for (int off = 1; off < 256; off <<= 1) {
        const int a = (t >= off) ? s[t - off] : 0;
        __syncthreads();
        s[t] += a;
        __syncthreads();
    }
    if (t < SCAN_BLOCKS) blockOff[t] = s[t] - v;  // exclusive
}

__global__ __launch_bounds__(256) void scanC_kernel(int* __restrict__ offs,
                                                    const int* __restrict__ blockOff,
                                                    float* __restrict__ statsbuf,  // 384 floats
                                                    float* __restrict__ pooled,    // B*64
                                                    unsigned int* __restrict__ qzero)  // Qh row NN (32 uints)
{
    const int i = blockIdx.x * 256 + threadIdx.x;
    if (i < NN) offs[i] += blockOff[blockIdx.x];
    if (i == 0) offs[NN] = EE;
    if (i < 384) statsbuf[i] = 0.f;
    if (i < BB * 64) pooled[i] = 0.f;
    if (blockIdx.x == 1 && threadIdx.x < 32) qzero[threadIdx.x] = 0u;
}

__global__ __launch_bounds__(256) void scatter_kernel(const int* __restrict__ src,
                                                      const int* __restrict__ dst,
                                                      const unsigned short* __restrict__ rank,
                                                      const int* __restrict__ offs,
                                                      unsigned short* __restrict__ srcSorted)
{
    const int e = blockIdx.x * 256 + threadIdx.x;  // exactly E threads
    const int pos = offs[dst[e]] + (int)rank[e];
    srcSorted[pos] = (unsigned short)src[e];
}

// ---------------- gather: Z[n] = Q[n] + b1 + sum_{src} Q[src]; fused BN column stats ----------------
// One wave per node slot; 16 lanes per row (8B/lane), 4 edges per load instruction.
// Per node: ALL 12 index loads issued, then ALL 12 row loads issued (invalid slots -> zero row NN),
// accumulate unconditionally. Two memory rounds per node regardless of degree (<=48);
// rare deg>48 handled by unmasked 48-edge blocks first.
__global__ __launch_bounds__(256) void gather_kernel(const __half2* __restrict__ Qh,
                                                     const int* __restrict__ offs,
                                                     const unsigned short* __restrict__ srcSorted,
                                                     const float* __restrict__ b1,
                                                     float* __restrict__ Z,
                                                     float* __restrict__ sums,   // [64]
                                                     float* __restrict__ sumsq)  // [64]
{
    const int tid  = threadIdx.x;
    const int lane = tid & 63;
    const int wid  = tid >> 6;        // wave in block: 0..3
    const int colq = lane & 15;       // column quad (4 halfs = 8B)
    const int grp  = lane >> 4;       // 0..3: edge slot within group-of-4
    const uint2* Qr = (const uint2*)Qh;   // 16 uint2 per row
    const float4 bb = ((const float4*)b1)[colq];

    float sa0 = 0.f, sa1 = 0.f, sa2 = 0.f, sa3 = 0.f;
    float ta0 = 0.f, ta1 = 0.f, ta2 = 0.f, ta3 = 0.f;

    for (int node = blockIdx.x * 4 + wid; node < NN; node += GATHER_BLOCKS * 4) {
        const int o0 = offs[node];
        const int o1 = offs[node + 1];
        float a0 = 0.f, a1 = 0.f, a2 = 0.f, a3 = 0.f;
        int j = o0;
        // rare: full unmasked 48-edge blocks
        while (o1 - j > 48) {
            int idx[12];
#pragma unroll
            for (int k = 0; k < 12; ++k) idx[k] = srcSorted[j + k * 4 + grp];
            uint2 r[12];
#pragma unroll
            for (int k = 0; k < 12; ++k) r[k] = Qr[(size_t)idx[k] * 16 + colq];
#pragma unroll
            for (int k = 0; k < 12; ++k) {
                float2 p;
                p = __half22float2(*(const __half2*)&r[k].x); a0 += p.x; a1 += p.y;
                p = __half22float2(*(const __half2*)&r[k].y); a2 += p.x; a3 += p.y;
            }
            j += 48;
        }
        // final masked 48-edge block (covers deg<=48 entirely)
        {
            int idx[12];
#pragma unroll
            for (int k = 0; k < 12; ++k) {
                const int p = j + k * 4 + grp;               // srcSorted padded by 64
                const int v = srcSorted[p];
                idx[k] = (p < o1) ? v : NN;                   // NN = zero row
            }
            uint2 r[12];
#pragma unroll
            for (int k = 0; k < 12; ++k) r[k] = Qr[(size_t)idx[k] * 16 + colq];
#pragma unroll
            for (int k = 0; k < 12; ++k) {
                float2 p;
                p = __half22float2(*(const __half2*)&r[k].x); a0 += p.x; a1 += p.y;
                p = __half22float2(*(const __half2*)&r[k].y); a2 += p.x; a3 += p.y;
            }
        }
        // combine the 4 edge-groups
        a0 += __shfl_xor(a0, 16); a1 += __shfl_xor(a1, 16);
        a2 += __shfl_xor(a2, 16); a3 += __shfl_xor(a3, 16);
        a0 += __shfl_xor(a0, 32); a1 += __shfl_xor(a1, 32);
        a2 += __shfl_xor(a2, 32); a3 += __shfl_xor(a3, 32);
        if (grp == 0) {
            const uint2 sr = Qr[(size_t)node * 16 + colq];
            float2 p;
            p = __half22float2(*(const __half2*)&sr.x); a0 += p.x + bb.x; a1 += p.y + bb.y;
            p = __half22float2(*(const __half2*)&sr.y); a2 += p.x + bb.z; a3 += p.y + bb.w;
            float4 zv = {a0, a1, a2, a3};
            ((float4*)Z)[(size_t)node * 16 + colq] = zv;
            sa0 += a0; sa1 += a1; sa2 += a2; sa3 += a3;
            ta0 += a0 * a0; ta1 += a1 * a1; ta2 += a2 * a2; ta3 += a3 * a3;
        }
    }

    // block-level stats reduce: 4 waves x 16 colq x 8 values -> 128 atomics
    __shared__ float red[4][16][8];
    if (grp == 0) {
        float* rp = red[wid][colq];
        rp[0] = sa0; rp[1] = sa1; rp[2] = sa2; rp[3] = sa3;
        rp[4] = ta0; rp[5] = ta1; rp[6] = ta2; rp[7] = ta3;
    }
    __syncthreads();
    if (tid < 128) {
        const int cq = tid >> 3;
        const int k  = tid & 7;
        const float v = red[0][cq][k] + red[1][cq][k] + red[2][cq][k] + red[3][cq][k];
        float* dstp = (k < 4) ? &sums[cq * 4 + k] : &sumsq[cq * 4 + (k - 4)];
        atomicAdd(dstp, v);
    }
}

// ---------------- gemm2: out = relu( relu(BN(Z)) @ W2 + b2 ); BN finalize in prologue ----------------
template <bool POOL>
__global__ __launch_bounds__(256) void gemm2_kernel(const float* __restrict__ Z,
                                                    const float* __restrict__ sums,
                                                    const float* __restrict__ sumsq,
                                                    const float* __restrict__ g1,
                                                    const float* __restrict__ bt1,
                                                    const float* __restrict__ W2,  // [64][64]
                                                    const float* __restrict__ b2,
                                                    const int* __restrict__ batch,
                                                    float* __restrict__ out)
{
    __shared__ float sW[64 * 64];
    __shared__ float sH[16 * 64];
    __shared__ float sScale[64];
    __shared__ float sShift[64];
    const int tid = threadIdx.x;
    const int row0 = blockIdx.x * 16;

    if (tid < 64) {
        const float inv_n = 1.0f / (float)NN;
        const float mean = sums[tid] * inv_n;
        const float var = fmaxf(sumsq[tid] * inv_n - mean * mean, 0.f);
        const float sc = g1[tid] * rsqrtf(var + BN_EPS);
        sScale[tid] = sc;
        sShift[tid] = bt1[tid] - mean * sc;
    }
    for (int i = tid; i < 64 * 16; i += 256)
        ((float4*)sW)[i] = ((const float4*)W2)[i];
    __syncthreads();

    const float4* Zb = (const float4*)(Z + (size_t)row0 * 64);
    {
        const int i = tid;  // 256 float4s = 16 rows x 16
        const float4 z = Zb[i];
        const int c4 = i & 15;
        const float4 sc = ((const float4*)sScale)[c4];
        const float4 sh = ((const float4*)sShift)[c4];
        float4 h;
        h.x = fmaxf(fmaf(z.x, sc.x, sh.x), 0.f);
        h.y = fmaxf(fmaf(z.y, sc.y, sh.y), 0.f);
        h.z = fmaxf(fmaf(z.z, sc.z, sh.z), 0.f);
        h.w = fmaxf(fmaf(z.w, sc.w, sh.w), 0.f);
        ((float4*)sH)[i] = h;
    }
    __syncthreads();

    const int col = tid & 63;
    const int r0  = tid >> 6;
    const float bc = b2[col];
    float acc[4] = {bc, bc, bc, bc};
    for (int k = 0; k < 64; k += 4) {
        const float w0 = sW[(k + 0) * 64 + col];
        const float w1 = sW[(k + 1) * 64 + col];
        const float w2 = sW[(k + 2) * 64 + col];
        const float w3 = sW[(k + 3) * 64 + col];
#pragma unroll
        for (int rr = 0; rr < 4; ++rr) {
            const float4 hv = *(const float4*)&sH[(r0 + rr * 4) * 64 + k];
            acc[rr] = fmaf(hv.x, w0, acc[rr]);
            acc[rr] = fmaf(hv.y, w1, acc[rr]);
            acc[rr] = fmaf(hv.z, w2, acc[rr]);
            acc[rr] = fmaf(hv.w, w3, acc[rr]);
        }
    }
#pragma unroll
    for (int rr = 0; rr < 4; ++rr) {
        const int row = row0 + r0 + rr * 4;
        const float v = fmaxf(acc[rr], 0.f);
        if (POOL) {
            atomicAdd(&out[(size_t)batch[row] * 64 + col], v);
        } else {
            out[(size_t)row * 64 + col] = v;
        }
    }
}

// ---------------- final MLP: out = relu(P @ fW1 + fb1) @ fW2 + fb2 ----------------
__global__ __launch_bounds__(256) void final_mlp(const float* __restrict__ P,   // [512][64]
                                                 const float* __restrict__ W1,  // [64][64]
                                                 const float* __restrict__ b1,
                                                 const float* __restrict__ W2,  // [64][32]
                                                 const float* __restrict__ b2,
                                                 float* __restrict__ out)       // [512][32]
{
    __shared__ float sW1[64 * 64];
    __shared__ float sW2[64 * 32];
    __shared__ float sH[4 * 64];
    const int tid = threadIdx.x;
    const int row0 = blockIdx.x * 4;

    for (int i = tid; i < 1024; i += 256) ((float4*)sW1)[i] = ((const float4*)W1)[i];
    for (int i = tid; i < 512; i += 256) ((float4*)sW2)[i] = ((const float4*)W2)[i];
    __syncthreads();

    const int col = tid & 63;
    const int r = tid >> 6;
    float acc = b1[col];
    const float* prow = P + (size_t)(row0 + r) * 64;
    for (int k = 0; k < 64; ++k) acc = fmaf(prow[k], sW1[k * 64 + col], acc);
    sH[r * 64 + col] = fmaxf(acc, 0.f);
    __syncthreads();

    if (tid < 128) {
        const int c = tid & 31;
        const int r2 = tid >> 5;
        float a2 = b2[c];
        for (int k = 0; k < 64; ++k) a2 = fmaf(sH[r2 * 64 + k], sW2[k * 32 + c], a2);
        out[(size_t)(row0 + r2) * 32 + c] = a2;
    }
}

extern "C" void kernel_launch(void* const* d_in, const int* in_sizes, int n_in,
                              void* d_out, int out_size, void* d_ws, size_t ws_size,
                              hipStream_t stream)
{
    const float* x   = (const float*)d_in[0];
    const int* ei    = (const int*)d_in[1];   // [2][E]: first E = src, next E = dst
    const int* batch = (const int*)d_in[2];
    const float* cW1[3] = {(const float*)d_in[4],  (const float*)d_in[10], (const float*)d_in[16]};
    const float* cb1[3] = {(const float*)d_in[5],  (const float*)d_in[11], (const float*)d_in[17]};
    const float* cg1[3] = {(const float*)d_in[6],  (const float*)d_in[12], (const float*)d_in[18]};
    const float* cbt[3] = {(const float*)d_in[7],  (const float*)d_in[13], (const float*)d_in[19]};
    const float* cW2[3] = {(const float*)d_in[8],  (const float*)d_in[14], (const float*)d_in[20]};
    const float* cb2[3] = {(const float*)d_in[9],  (const float*)d_in[15], (const float*)d_in[21]};
    const float* fW1 = (const float*)d_in[22];
    const float* fb1 = (const float*)d_in[23];
    const float* fW2 = (const float*)d_in[24];
    const float* fb2 = (const float*)d_in[25];
    float* out = (float*)d_out;

    // workspace layout
    float* bufX     = (float*)d_ws;                        // N*64 fp32: X for layers>=1, Z (in-place safe)
    __half2* Qh     = (__half2*)(bufX + (size_t)NN * 64);  // (N+1)*32 half2 (row NN = zero row)
    float* pooled   = (float*)(Qh + (size_t)(NN + 1) * 32);// B*64
    float* statsbuf = pooled + (size_t)BB * 64;            // 3 layers x (64 sums + 64 sumsq)
    int* deg        = (int*)(statsbuf + 384);              // N
    int* offs       = deg + NN;                            // N+1
    int* blockSums  = offs + (NN + 1);                     // 256
    int* blockOff   = blockSums + 256;                     // 256
    unsigned short* rank      = (unsigned short*)(blockOff + 256);  // E
    unsigned short* srcSorted = rank + EE;                          // E + 64 (padded)

    const int* esrc = ei;
    const int* edst = ei + EE;

    const int gemm_blocks = NN / 16;   // 3125
    const int edge_blocks = EE / 256;  // 3125

    // ---- build CSR by dst ----
    hipMemsetAsync(deg, 0, NN * sizeof(int), stream);
    hist_rank_kernel<<<edge_blocks, 256, 0, stream>>>(edst, deg, rank);
    scanA_kernel<<<SCAN_BLOCKS, 256, 0, stream>>>(deg, offs, blockSums);
    scanB_kernel<<<1, 256, 0, stream>>>(blockSums, blockOff);
    scanC_kernel<<<SCAN_BLOCKS, 256, 0, stream>>>(offs, blockOff, statsbuf, pooled,
                                                  (unsigned int*)(Qh + (size_t)NN * 32));
    scatter_kernel<<<edge_blocks, 256, 0, stream>>>(esrc, edst, rank, offs, srcSorted);

    for (int layer = 0; layer < 3; ++layer) {
        float* sums  = statsbuf + layer * 128;
        float* sumsq = sums + 64;

        // 1) projection Qh = half(x_cur @ W1)
        if (layer == 0)
            proj_kernel<DIN><<<gemm_blocks, 256, 0, stream>>>(x, cW1[0], Qh);
        else
            proj_kernel<HH><<<gemm_blocks, 256, 0, stream>>>(bufX, cW1[layer], Qh);

        // 2) gather-aggregate + fused BN stats (Z aliases bufX; gemm2 is row-local in-place)
        gather_kernel<<<GATHER_BLOCKS, 256, 0, stream>>>(Qh, offs, srcSorted, cb1[layer],
                                                         bufX, sums, sumsq);

        // 3) BN finalize (in gemm2 prologue) + second linear + ReLU; last layer fuses pooling
        if (layer < 2) {
            gemm2_kernel<false><<<gemm_blocks, 256, 0, stream>>>(bufX, sums, sumsq, cg1[layer],
                                                                 cbt[layer], cW2[layer], cb2[layer],
                                                                 nullptr, bufX);
        } else {
            gemm2_kernel<true><<<gemm_blocks, 256, 0, stream>>>(bufX, sums, sumsq, cg1[layer],
                                                                cbt[layer], cW2[layer], cb2[layer],
                                                                batch, pooled);
        }
    }

    // final MLP on pooled graph features
    final_mlp<<<BB / 4, 256, 0, stream>>>(pooled, fW1, fb1, fW2, fb2, out);
}

// Round 6
// 377.242 us; speedup vs baseline: 1.0137x; 1.0137x over previous
//
#include <hip/hip_runtime.h>
#include <hip/hip_fp16.h>

#define NN 50000
#define EE 800000
#define BB 512
#define DIN 128
#define HH 64
#define DOUT 32
#define BN_EPS 1e-5f
#define SCAN_BLOCKS 196   // ceil(50000/256)
#define GATHER_BLOCKS 2048

// ---------------- proj: Qh = half(X @ W)  (no bias; bias folded into gather) ----------------
template <int CIN>
__global__ __launch_bounds__(256) void proj_kernel(const float* __restrict__ X,
                                                   const float* __restrict__ W,  // [CIN][64]
                                                   __half2* __restrict__ Qh)     // [N+1][32]
{
    __shared__ float sW[CIN * 64];
    __shared__ float sX[16 * CIN];
    const int tid = threadIdx.x;
    const int row0 = blockIdx.x * 16;

    for (int i = tid; i < CIN * 16; i += 256)
        ((float4*)sW)[i] = ((const float4*)W)[i];
    const float* Xb = X + (size_t)row0 * CIN;
    for (int i = tid; i < 16 * CIN / 4; i += 256)
        ((float4*)sX)[i] = ((const float4*)Xb)[i];
    __syncthreads();

    const int col2 = tid & 31;   // column pair
    const int rg   = tid >> 5;   // 0..7 -> rows rg*2, rg*2+1
    float2 acc0 = {0.f, 0.f};
    float2 acc1 = {0.f, 0.f};
    const float* x0p = &sX[(rg * 2 + 0) * CIN];
    const float* x1p = &sX[(rg * 2 + 1) * CIN];
#pragma unroll 4
    for (int k = 0; k < CIN; ++k) {
        const float2 w = *(const float2*)&sW[k * 64 + col2 * 2];
        const float x0 = x0p[k];
        const float x1 = x1p[k];
        acc0.x = fmaf(x0, w.x, acc0.x);
        acc0.y = fmaf(x0, w.y, acc0.y);
        acc1.x = fmaf(x1, w.x, acc1.x);
        acc1.y = fmaf(x1, w.y, acc1.y);
    }
    const int r0 = row0 + rg * 2;
    Qh[(size_t)(r0 + 0) * 32 + col2] = __floats2half2_rn(acc0.x, acc0.y);
    Qh[(size_t)(r0 + 1) * 32 + col2] = __floats2half2_rn(acc1.x, acc1.y);
}

// ---------------- CSR build ----------------
__global__ __launch_bounds__(256) void hist_rank_kernel(const int* __restrict__ dst,
                                                        int* __restrict__ deg,
                                                        unsigned short* __restrict__ rank)
{
    const int e = blockIdx.x * 256 + threadIdx.x;  // exactly E threads
    rank[e] = (unsigned short)atomicAdd(&deg[dst[e]], 1);
}

__global__ __launch_bounds__(256) void scanA_kernel(const int* __restrict__ deg,
                                                    int* __restrict__ offs,
                                                    int* __restrict__ blockSums)
{
    __shared__ int s[256];
    const int t = threadIdx.x;
    const int i = blockIdx.x * 256 + t;
    const int v = (i < NN) ? deg[i] : 0;
    s[t] = v;
    __syncthreads();
    for (int off = 1; off < 256; off <<= 1) {
        const int a = (t >= off) ? s[t - off] : 0;
        __syncthreads();
        s[t] += a;
        __syncthreads();
    }
    if (i < NN) offs[i] = s[t] - v;  // exclusive intra-block
    if (t == 255) blockSums[blockIdx.x] = s[255];
}

__global__ __launch_bounds__(256) void scanB_kernel(const int* __restrict__ blockSums,
                                                    int* __restrict__ blockOff)
{
    __shared__ int s[256];
    const int t = threadIdx.x;
    const int v = (t < SCAN_BLOCKS) ? blockSums[t] : 0;
    s[t] = v;
    __syncthreads();
    for (int off = 1; off < 256; off <<= 1) {
        const int a = (t >= off) ? s[t - off] : 0;
        __syncthreads();
        s[t] += a;
        __syncthreads();
    }
    if (t < SCAN_BLOCKS) blockOff[t] = s[t] - v;  // exclusive
}

__global__ __launch_bounds__(256) void scanC_kernel(int* __restrict__ offs,
                                                    const int* __restrict__ blockOff,
                                                    float* __restrict__ statsbuf,  // 384 floats
                                                    float* __restrict__ pooled,    // B*64
                                                    unsigned int* __restrict__ qzero)  // Qh row NN (32 uints)
{
    const int i = blockIdx.x * 256 + threadIdx.x;
    if (i < NN) offs[i] += blockOff[blockIdx.x];
    if (i == 0) offs[NN] = EE;
    if (i < 384) statsbuf[i] = 0.f;
    if (i < BB * 64) pooled[i] = 0.f;
    if (blockIdx.x == 1 && threadIdx.x < 32) qzero[threadIdx.x] = 0u;
}

__global__ __launch_bounds__(256) void scatter_kernel(const int* __restrict__ src,
                                                      const int* __restrict__ dst,
                                                      const unsigned short* __restrict__ rank,
                                                      const int* __restrict__ offs,
                                                      unsigned short* __restrict__ srcSorted)
{
    const int e = blockIdx.x * 256 + threadIdx.x;  // exactly E threads
    const int pos = offs[dst[e]] + (int)rank[e];
    srcSorted[pos] = (unsigned short)src[e];
}

// accumulate 8 halfs (one uint4) into a[0..7]
#define ACC8(a, r)                                                              \
    do {                                                                        \
        float2 p_;                                                              \
        p_ = __half22float2(*(const __half2*)&(r).x); a[0] += p_.x; a[1] += p_.y; \
        p_ = __half22float2(*(const __half2*)&(r).y); a[2] += p_.x; a[3] += p_.y; \
        p_ = __half22float2(*(const __half2*)&(r).z); a[4] += p_.x; a[5] += p_.y; \
        p_ = __half22float2(*(const __half2*)&(r).w); a[6] += p_.x; a[7] += p_.y; \
    } while (0)

// ---------------- gather: Z[n] = Q[n] + b1 + sum_{src} Q[src]; fused BN column stats ----------------
// One wave per node slot; 8 lanes per row (16B uint4/lane) -> 8 edges per load instruction.
// Degree-adaptive masking: 32-edge masked double-blocks while >16 edges remain, then one
// 16-edge masked block. Invalid slots load zero row NN (L1-resident). For deg<=32 (99.98%),
// exactly one idx-round + one row-round on the critical path.
__global__ __launch_bounds__(256) void gather_kernel(const __half2* __restrict__ Qh,
                                                     const int* __restrict__ offs,
                                                     const unsigned short* __restrict__ srcSorted,
                                                     const float* __restrict__ b1,
                                                     float* __restrict__ Z,
                                                     float* __restrict__ sums,   // [64]
                                                     float* __restrict__ sumsq)  // [64]
{
    const int tid  = threadIdx.x;
    const int lane = tid & 63;
    const int wid  = tid >> 6;        // wave in block: 0..3
    const int colo = lane & 7;        // column octet (8 halfs = 16B)
    const int slot = lane >> 3;       // 0..7: edge slot
    const uint4* Qr = (const uint4*)Qh;   // 8 uint4 per row
    const float4 bbA = ((const float4*)b1)[colo * 2 + 0];
    const float4 bbB = ((const float4*)b1)[colo * 2 + 1];

    float sa[8] = {0, 0, 0, 0, 0, 0, 0, 0};
    float ta[8] = {0, 0, 0, 0, 0, 0, 0, 0};

    for (int node = blockIdx.x * 4 + wid; node < NN; node += GATHER_BLOCKS * 4) {
        const int o0 = offs[node];
        const int o1 = offs[node + 1];
        float a[8] = {0, 0, 0, 0, 0, 0, 0, 0};
        int j = o0;
        while (o1 - j > 16) {
            // 32-edge masked double-block (first 16 always valid)
            const int p2 = j + 16 + slot;
            const int p3 = j + 24 + slot;
            const int i0 = srcSorted[j + slot];
            const int i1 = srcSorted[j + 8 + slot];
            const int v2 = srcSorted[p2];
            const int v3 = srcSorted[p3];
            const int i2 = (p2 < o1) ? v2 : NN;
            const int i3 = (p3 < o1) ? v3 : NN;
            const uint4 r0 = Qr[(size_t)i0 * 8 + colo];
            const uint4 r1 = Qr[(size_t)i1 * 8 + colo];
            const uint4 r2 = Qr[(size_t)i2 * 8 + colo];
            const uint4 r3 = Qr[(size_t)i3 * 8 + colo];
            ACC8(a, r0);
            ACC8(a, r1);
            ACC8(a, r2);
            ACC8(a, r3);
            j += 32;
        }
        if (j < o1) {
            // final 16-edge masked block
            const int p0 = j + slot;
            const int p1 = j + 8 + slot;
            const int v0 = srcSorted[p0];
            const int v1 = srcSorted[p1];
            const int i0 = (p0 < o1) ? v0 : NN;
            const int i1 = (p1 < o1) ? v1 : NN;
            const uint4 r0 = Qr[(size_t)i0 * 8 + colo];
            const uint4 r1 = Qr[(size_t)i1 * 8 + colo];
            ACC8(a, r0);
            ACC8(a, r1);
        }
        // reduce across the 8 slots (xor 8, 16, 32)
#pragma unroll
        for (int k = 0; k < 8; ++k) a[k] += __shfl_xor(a[k], 8);
#pragma unroll
        for (int k = 0; k < 8; ++k) a[k] += __shfl_xor(a[k], 16);
#pragma unroll
        for (int k = 0; k < 8; ++k) a[k] += __shfl_xor(a[k], 32);
        if (slot == 0) {
            const uint4 sr = Qr[(size_t)node * 8 + colo];
            float2 p;
            p = __half22float2(*(const __half2*)&sr.x); a[0] += p.x + bbA.x; a[1] += p.y + bbA.y;
            p = __half22float2(*(const __half2*)&sr.y); a[2] += p.x + bbA.z; a[3] += p.y + bbA.w;
            p = __half22float2(*(const __half2*)&sr.z); a[4] += p.x + bbB.x; a[5] += p.y + bbB.y;
            p = __half22float2(*(const __half2*)&sr.w); a[6] += p.x + bbB.z; a[7] += p.y + bbB.w;
            const float4 z0 = {a[0], a[1], a[2], a[3]};
            const float4 z1 = {a[4], a[5], a[6], a[7]};
            ((float4*)Z)[(size_t)node * 16 + colo * 2 + 0] = z0;
            ((float4*)Z)[(size_t)node * 16 + colo * 2 + 1] = z1;
#pragma unroll
            for (int k = 0; k < 8; ++k) {
                sa[k] += a[k];
                ta[k] += a[k] * a[k];
            }
        }
    }

    // block-level stats reduce: 4 waves x 8 colo x 16 values -> 128 atomics
    __shared__ float red[4][8][16];
    if (slot == 0) {
#pragma unroll
        for (int k = 0; k < 8; ++k) {
            red[wid][colo][k]     = sa[k];
            red[wid][colo][8 + k] = ta[k];
        }
    }
    __syncthreads();
    if (tid < 128) {
        const int co = tid >> 4;   // 0..7
        const int k  = tid & 15;   // 0..15
        const float v = red[0][co][k] + red[1][co][k] + red[2][co][k] + red[3][co][k];
        float* dstp = (k < 8) ? &sums[co * 8 + k] : &sumsq[co * 8 + (k - 8)];
        atomicAdd(dstp, v);
    }
}

// ---------------- gemm2: out = relu( relu(BN(Z)) @ W2 + b2 ); BN finalize in prologue ----------------
template <bool POOL>
__global__ __launch_bounds__(256) void gemm2_kernel(const float* __restrict__ Z,
                                                    const float* __restrict__ sums,
                                                    const float* __restrict__ sumsq,
                                                    const float* __restrict__ g1,
                                                    const float* __restrict__ bt1,
                                                    const float* __restrict__ W2,  // [64][64]
                                                    const float* __restrict__ b2,
                                                    const int* __restrict__ batch,
                                                    float* __restrict__ out)
{
    __shared__ float sW[64 * 64];
    __shared__ float sH[16 * 64];
    __shared__ float sScale[64];
    __shared__ float sShift[64];
    const int tid = threadIdx.x;
    const int row0 = blockIdx.x * 16;

    if (tid < 64) {
        const float inv_n = 1.0f / (float)NN;
        const float mean = sums[tid] * inv_n;
        const float var = fmaxf(sumsq[tid] * inv_n - mean * mean, 0.f);
        const float sc = g1[tid] * rsqrtf(var + BN_EPS);
        sScale[tid] = sc;
        sShift[tid] = bt1[tid] - mean * sc;
    }
    for (int i = tid; i < 64 * 16; i += 256)
        ((float4*)sW)[i] = ((const float4*)W2)[i];
    __syncthreads();

    const float4* Zb = (const float4*)(Z + (size_t)row0 * 64);
    {
        const int i = tid;  // 256 float4s = 16 rows x 16
        const float4 z = Zb[i];
        const int c4 = i & 15;
        const float4 sc = ((const float4*)sScale)[c4];
        const float4 sh = ((const float4*)sShift)[c4];
        float4 h;
        h.x = fmaxf(fmaf(z.x, sc.x, sh.x), 0.f);
        h.y = fmaxf(fmaf(z.y, sc.y, sh.y), 0.f);
        h.z = fmaxf(fmaf(z.z, sc.z, sh.z), 0.f);
        h.w = fmaxf(fmaf(z.w, sc.w, sh.w), 0.f);
        ((float4*)sH)[i] = h;
    }
    __syncthreads();

    const int col = tid & 63;
    const int r0  = tid >> 6;
    const float bc = b2[col];
    float acc[4] = {bc, bc, bc, bc};
    for (int k = 0; k < 64; k += 4) {
        const float w0 = sW[(k + 0) * 64 + col];
        const float w1 = sW[(k + 1) * 64 + col];
        const float w2 = sW[(k + 2) * 64 + col];
        const float w3 = sW[(k + 3) * 64 + col];
#pragma unroll
        for (int rr = 0; rr < 4; ++rr) {
            const float4 hv = *(const float4*)&sH[(r0 + rr * 4) * 64 + k];
            acc[rr] = fmaf(hv.x, w0, acc[rr]);
            acc[rr] = fmaf(hv.y, w1, acc[rr]);
            acc[rr] = fmaf(hv.z, w2, acc[rr]);
            acc[rr] = fmaf(hv.w, w3, acc[rr]);
        }
    }
#pragma unroll
    for (int rr = 0; rr < 4; ++rr) {
        const int row = row0 + r0 + rr * 4;
        const float v = fmaxf(acc[rr], 0.f);
        if (POOL) {
            atomicAdd(&out[(size_t)batch[row] * 64 + col], v);
        } else {
            out[(size_t)row * 64 + col] = v;
        }
    }
}

// ---------------- final MLP: out = relu(P @ fW1 + fb1) @ fW2 + fb2 ----------------
__global__ __launch_bounds__(256) void final_mlp(const float* __restrict__ P,   // [512][64]
                                                 const float* __restrict__ W1,  // [64][64]
                                                 const float* __restrict__ b1,
                                                 const float* __restrict__ W2,  // [64][32]
                                                 const float* __restrict__ b2,
                                                 float* __restrict__ out)       // [512][32]
{
    __shared__ float sW1[64 * 64];
    __shared__ float sW2[64 * 32];
    __shared__ float sH[4 * 64];
    const int tid = threadIdx.x;
    const int row0 = blockIdx.x * 4;

    for (int i = tid; i < 1024; i += 256) ((float4*)sW1)[i] = ((const float4*)W1)[i];
    for (int i = tid; i < 512; i += 256) ((float4*)sW2)[i] = ((const float4*)W2)[i];
    __syncthreads();

    const int col = tid & 63;
    const int r = tid >> 6;
    float acc = b1[col];
    const float* prow = P + (size_t)(row0 + r) * 64;
    for (int k = 0; k < 64; ++k) acc = fmaf(prow[k], sW1[k * 64 + col], acc);
    sH[r * 64 + col] = fmaxf(acc, 0.f);
    __syncthreads();

    if (tid < 128) {
        const int c = tid & 31;
        const int r2 = tid >> 5;
        float a2 = b2[c];
        for (int k = 0; k < 64; ++k) a2 = fmaf(sH[r2 * 64 + k], sW2[k * 32 + c], a2);
        out[(size_t)(row0 + r2) * 32 + c] = a2;
    }
}

extern "C" void kernel_launch(void* const* d_in, const int* in_sizes, int n_in,
                              void* d_out, int out_size, void* d_ws, size_t ws_size,
                              hipStream_t stream)
{
    const float* x   = (const float*)d_in[0];
    const int* ei    = (const int*)d_in[1];   // [2][E]: first E = src, next E = dst
    const int* batch = (const int*)d_in[2];
    const float* cW1[3] = {(const float*)d_in[4],  (const float*)d_in[10], (const float*)d_in[16]};
    const float* cb1[3] = {(const float*)d_in[5],  (const float*)d_in[11], (const float*)d_in[17]};
    const float* cg1[3] = {(const float*)d_in[6],  (const float*)d_in[12], (const float*)d_in[18]};
    const float* cbt[3] = {(const float*)d_in[7],  (const float*)d_in[13], (const float*)d_in[19]};
    const float* cW2[3] = {(const float*)d_in[8],  (const float*)d_in[14], (const float*)d_in[20]};
    const float* cb2[3] = {(const float*)d_in[9],  (const float*)d_in[15], (const float*)d_in[21]};
    const float* fW1 = (const float*)d_in[22];
    const float* fb1 = (const float*)d_in[23];
    const float* fW2 = (const float*)d_in[24];
    const float* fb2 = (const float*)d_in[25];
    float* out = (float*)d_out;

    // workspace layout
    float* bufX     = (float*)d_ws;                        // N*64 fp32: X for layers>=1, Z (in-place safe)
    __half2* Qh     = (__half2*)(bufX + (size_t)NN * 64);  // (N+1)*32 half2 (row NN = zero row)
    float* pooled   = (float*)(Qh + (size_t)(NN + 1) * 32);// B*64
    float* statsbuf = pooled + (size_t)BB * 64;            // 3 layers x (64 sums + 64 sumsq)
    int* deg        = (int*)(statsbuf + 384);              // N
    int* offs       = deg + NN;                            // N+1
    int* blockSums  = offs + (NN + 1);                     // 256
    int* blockOff   = blockSums + 256;                     // 256
    unsigned short* rank      = (unsigned short*)(blockOff + 256);  // E
    unsigned short* srcSorted = rank + EE;                          // E + 64 (padded)

    const int* esrc = ei;
    const int* edst = ei + EE;

    const int gemm_blocks = NN / 16;   // 3125
    const int edge_blocks = EE / 256;  // 3125

    // ---- build CSR by dst ----
    hipMemsetAsync(deg, 0, NN * sizeof(int), stream);
    hist_rank_kernel<<<edge_blocks, 256, 0, stream>>>(edst, deg, rank);
    scanA_kernel<<<SCAN_BLOCKS, 256, 0, stream>>>(deg, offs, blockSums);
    scanB_kernel<<<1, 256, 0, stream>>>(blockSums, blockOff);
    scanC_kernel<<<SCAN_BLOCKS, 256, 0, stream>>>(offs, blockOff, statsbuf, pooled,
                                                  (unsigned int*)(Qh + (size_t)NN * 32));
    scatter_kernel<<<edge_blocks, 256, 0, stream>>>(esrc, edst, rank, offs, srcSorted);

    for (int layer = 0; layer < 3; ++layer) {
        float* sums  = statsbuf + layer * 128;
        float* sumsq = sums + 64;

        // 1) projection Qh = half(x_cur @ W1)
        if (layer == 0)
            proj_kernel<DIN><<<gemm_blocks, 256, 0, stream>>>(x, cW1[0], Qh);
        else
            proj_kernel<HH><<<gemm_blocks, 256, 0, stream>>>(bufX, cW1[layer], Qh);

        // 2) gather-aggregate + fused BN stats (Z aliases bufX; gemm2 is row-local in-place)
        gather_kernel<<<GATHER_BLOCKS, 256, 0, stream>>>(Qh, offs, srcSorted, cb1[layer],
                                                         bufX, sums, sumsq);

        // 3) BN finalize (in gemm2 prologue) + second linear + ReLU; last layer fuses pooling
        if (layer < 2) {
            gemm2_kernel<false><<<gemm_blocks, 256, 0, stream>>>(bufX, sums, sumsq, cg1[layer],
                                                                 cbt[layer], cW2[layer], cb2[layer],
                                                                 nullptr, bufX);
        } else {
            gemm2_kernel<true><<<gemm_blocks, 256, 0, stream>>>(bufX, sums, sumsq, cg1[layer],
                                                                cbt[layer], cW2[layer], cb2[layer],
                                                                batch, pooled);
        }
    }

    // final MLP on pooled graph features
    final_mlp<<<BB / 4, 256, 0, stream>>>(pooled, fW1, fb1, fW2, fb2, out);
}

// Round 7
// 365.054 us; speedup vs baseline: 1.0475x; 1.0334x over previous
//
#include <hip/hip_runtime.h>
#include <hip/hip_fp16.h>

#define NN 50000
#define EE 800000
#define BB 512
#define DIN 128
#define HH 64
#define DOUT 32
#define BN_EPS 1e-5f
#define SCAN_BLOCKS 196   // ceil(50000/256)
#define GATHER_BLOCKS 2048
#define PADMAX (16 * NN + EE + 64)   // worst-case padded CSR entries

// ---------------- proj: Qh = half(X @ W)  (no bias; bias folded into gather) ----------------
template <int CIN>
__global__ __launch_bounds__(256) void proj_kernel(const float* __restrict__ X,
                                                   const float* __restrict__ W,  // [CIN][64]
                                                   __half2* __restrict__ Qh)     // [N+1][32]
{
    __shared__ float sW[CIN * 64];
    __shared__ float sX[16 * CIN];
    const int tid = threadIdx.x;
    const int row0 = blockIdx.x * 16;

    for (int i = tid; i < CIN * 16; i += 256)
        ((float4*)sW)[i] = ((const float4*)W)[i];
    const float* Xb = X + (size_t)row0 * CIN;
    for (int i = tid; i < 16 * CIN / 4; i += 256)
        ((float4*)sX)[i] = ((const float4*)Xb)[i];
    __syncthreads();

    const int col2 = tid & 31;   // column pair
    const int rg   = tid >> 5;   // 0..7 -> rows rg*2, rg*2+1
    float2 acc0 = {0.f, 0.f};
    float2 acc1 = {0.f, 0.f};
    const float* x0p = &sX[(rg * 2 + 0) * CIN];
    const float* x1p = &sX[(rg * 2 + 1) * CIN];
#pragma unroll 4
    for (int k = 0; k < CIN; ++k) {
        const float2 w = *(const float2*)&sW[k * 64 + col2 * 2];
        const float x0 = x0p[k];
        const float x1 = x1p[k];
        acc0.x = fmaf(x0, w.x, acc0.x);
        acc0.y = fmaf(x0, w.y, acc0.y);
        acc1.x = fmaf(x1, w.x, acc1.x);
        acc1.y = fmaf(x1, w.y, acc1.y);
    }
    const int r0 = row0 + rg * 2;
    Qh[(size_t)(r0 + 0) * 32 + col2] = __floats2half2_rn(acc0.x, acc0.y);
    Qh[(size_t)(r0 + 1) * 32 + col2] = __floats2half2_rn(acc1.x, acc1.y);
}

// ---------------- padded-CSR build ----------------
__global__ __launch_bounds__(256) void fill_kernel(unsigned int* __restrict__ dstw)
{
    const int i = blockIdx.x * 256 + threadIdx.x;
    if (i < PADMAX / 2) dstw[i] = 0xC350C350u;  // NN = 50000 = 0xC350 in both halves
}

__global__ __launch_bounds__(256) void hist_rank_kernel(const int* __restrict__ dst,
                                                        int* __restrict__ deg,
                                                        unsigned short* __restrict__ rank)
{
    const int e = blockIdx.x * 256 + threadIdx.x;  // exactly E threads
    rank[e] = (unsigned short)atomicAdd(&deg[dst[e]], 1);
}

// scan over padded capacities cap = max(16, roundup16(deg))
__global__ __launch_bounds__(256) void scanA_kernel(const int* __restrict__ deg,
                                                    int* __restrict__ poffs,
                                                    int* __restrict__ blockSums)
{
    __shared__ int s[256];
    const int t = threadIdx.x;
    const int i = blockIdx.x * 256 + t;
    int v = 0;
    if (i < NN) {
        const int d = deg[i];
        v = (d <= 16) ? 16 : ((d + 15) & ~15);
    }
    s[t] = v;
    __syncthreads();
    for (int off = 1; off < 256; off <<= 1) {
        const int a = (t >= off) ? s[t - off] : 0;
        __syncthreads();
        s[t] += a;
        __syncthreads();
    }
    if (i < NN) poffs[i] = s[t] - v;  // exclusive intra-block
    if (t == 255) blockSums[blockIdx.x] = s[255];
}

__global__ __launch_bounds__(256) void scanB_kernel(const int* __restrict__ blockSums,
                                                    int* __restrict__ blockOff,
                                                    int* __restrict__ poffs)
{
    __shared__ int s[256];
    const int t = threadIdx.x;
    const int v = (t < SCAN_BLOCKS) ? blockSums[t] : 0;
    s[t] = v;
    __syncthreads();
    for (int off = 1; off < 256; off <<= 1) {
        const int a = (t >= off) ? s[t - off] : 0;
        __syncthreads();
        s[t] += a;
        __syncthreads();
    }
    if (t < SCAN_BLOCKS) blockOff[t] = s[t] - v;  // exclusive
    if (t == SCAN_BLOCKS - 1) poffs[NN] = s[t];   // total padded size
}

__global__ __launch_bounds__(256) void scanC_kernel(int* __restrict__ poffs,
                                                    const int* __restrict__ blockOff,
                                                    float* __restrict__ statsbuf,  // 384 floats
                                                    float* __restrict__ pooled,    // B*64
                                                    unsigned int* __restrict__ qzero)  // Qh row NN
{
    const int i = blockIdx.x * 256 + threadIdx.x;
    if (i < NN) poffs[i] += blockOff[blockIdx.x];
    if (i < 384) statsbuf[i] = 0.f;
    if (i < BB * 64) pooled[i] = 0.f;
    if (blockIdx.x == 1 && threadIdx.x < 32) qzero[threadIdx.x] = 0u;
}

__global__ __launch_bounds__(256) void scatter_kernel(const int* __restrict__ src,
                                                      const int* __restrict__ dst,
                                                      const unsigned short* __restrict__ rank,
                                                      const int* __restrict__ poffs,
                                                      unsigned short* __restrict__ srcPadded)
{
    const int e = blockIdx.x * 256 + threadIdx.x;  // exactly E threads
    const int pos = poffs[dst[e]] + (int)rank[e];
    srcPadded[pos] = (unsigned short)src[e];
}

// ---------------- gather: Z[n] = Q[n] + b1 + sum_{src} Q[src]; fused BN column stats ----------------
// Column-parallel: lane c=lane&31 owns columns {2c,2c+1}; grp=lane>>5 takes alternate edges.
// Padded CSR (16-edge chunks, pad index = NN -> L1-resident zero row): no masking, no predication.
// Chunks 0+1 hoisted: up to 16 independent 128B row loads in flight per wave.
__global__ __launch_bounds__(256) void gather_kernel(const __half2* __restrict__ Qh,
                                                     const int* __restrict__ poffs,
                                                     const unsigned short* __restrict__ srcPadded,
                                                     const float* __restrict__ b1,
                                                     float* __restrict__ Z,
                                                     float* __restrict__ sums,   // [64]
                                                     float* __restrict__ sumsq)  // [64]
{
    const int tid   = threadIdx.x;
    const int lane  = tid & 63;
    const int wid   = tid >> 6;       // wave in block: 0..3
    const int c     = lane & 31;      // column pair {2c, 2c+1}
    const int grp   = lane >> 5;      // 0/1: edge parity
    const int shamt = grp << 4;       // 0 or 16
    const uint* Qd  = (const uint*)Qh;   // 32 dwords per row
    const float2 bb = ((const float2*)b1)[c];

    float2 sa = {0.f, 0.f};
    float2 ta = {0.f, 0.f};

    for (int node = blockIdx.x * 4 + wid; node < NN; node += GATHER_BLOCKS * 4) {
        const int p0 = poffs[node];
        const int p1 = poffs[node + 1];
        const bool two = (p1 - p0) > 16;

        // broadcast index loads (32B-aligned by construction)
        const uint4 ia = *(const uint4*)(srcPadded + p0);
        const uint4 ib = *(const uint4*)(srcPadded + p0 + 8);
        uint4 ia2, ib2;
        if (two) {
            ia2 = *(const uint4*)(srcPadded + p0 + 16);
            ib2 = *(const uint4*)(srcPadded + p0 + 24);
        }
        const uint sr = Qd[(size_t)node * 32 + c];  // self row, issued early

        // row loads: 8 (or 16) independent
        uint r[16];
#pragma unroll
        for (int k = 0; k < 4; ++k) {
            r[k]     = Qd[(size_t)(((&ia.x)[k] >> shamt) & 0xffffu) * 32 + c];
            r[4 + k] = Qd[(size_t)(((&ib.x)[k] >> shamt) & 0xffffu) * 32 + c];
        }
        if (two) {
#pragma unroll
            for (int k = 0; k < 4; ++k) {
                r[8 + k]  = Qd[(size_t)(((&ia2.x)[k] >> shamt) & 0xffffu) * 32 + c];
                r[12 + k] = Qd[(size_t)(((&ib2.x)[k] >> shamt) & 0xffffu) * 32 + c];
            }
        }

        float2 acc = {0.f, 0.f};
#pragma unroll
        for (int k = 0; k < 8; ++k) {
            const float2 p = __half22float2(*(const __half2*)&r[k]);
            acc.x += p.x;
            acc.y += p.y;
        }
        if (two) {
#pragma unroll
            for (int k = 8; k < 16; ++k) {
                const float2 p = __half22float2(*(const __half2*)&r[k]);
                acc.x += p.x;
                acc.y += p.y;
            }
        }
        // rare: degree > 32
        for (int j = p0 + 32; j < p1; j += 16) {
            const uint4 ja = *(const uint4*)(srcPadded + j);
            const uint4 jb = *(const uint4*)(srcPadded + j + 8);
            uint rr[8];
#pragma unroll
            for (int k = 0; k < 4; ++k) {
                rr[k]     = Qd[(size_t)(((&ja.x)[k] >> shamt) & 0xffffu) * 32 + c];
                rr[4 + k] = Qd[(size_t)(((&jb.x)[k] >> shamt) & 0xffffu) * 32 + c];
            }
#pragma unroll
            for (int k = 0; k < 8; ++k) {
                const float2 p = __half22float2(*(const __half2*)&rr[k]);
                acc.x += p.x;
                acc.y += p.y;
            }
        }

        // combine the two edge-parity groups
        acc.x += __shfl_xor(acc.x, 32);
        acc.y += __shfl_xor(acc.y, 32);

        if (grp == 0) {
            const float2 p = __half22float2(*(const __half2*)&sr);
            acc.x += p.x + bb.x;
            acc.y += p.y + bb.y;
            ((float2*)Z)[(size_t)node * 32 + c] = acc;
            sa.x += acc.x; sa.y += acc.y;
            ta.x += acc.x * acc.x; ta.y += acc.y * acc.y;
        }
    }

    // block-level stats reduce: 4 waves x 32 lanes x 4 values -> 128 atomics
    __shared__ float red[4][32][4];
    if (grp == 0) {
        float* rp = red[wid][c];
        rp[0] = sa.x; rp[1] = sa.y; rp[2] = ta.x; rp[3] = ta.y;
    }
    __syncthreads();
    if (tid < 128) {
        const int c2 = tid >> 2;   // 0..31
        const int k  = tid & 3;    // 0..3
        const float v = red[0][c2][k] + red[1][c2][k] + red[2][c2][k] + red[3][c2][k];
        float* dstp;
        if (k == 0)      dstp = &sums[2 * c2 + 0];
        else if (k == 1) dstp = &sums[2 * c2 + 1];
        else if (k == 2) dstp = &sumsq[2 * c2 + 0];
        else             dstp = &sumsq[2 * c2 + 1];
        atomicAdd(dstp, v);
    }
}

// ---------------- gemm2: out = relu( relu(BN(Z)) @ W2 + b2 ); BN finalize in prologue ----------------
template <bool POOL>
__global__ __launch_bounds__(256) void gemm2_kernel(const float* __restrict__ Z,
                                                    const float* __restrict__ sums,
                                                    const float* __restrict__ sumsq,
                                                    const float* __restrict__ g1,
                                                    const float* __restrict__ bt1,
                                                    const float* __restrict__ W2,  // [64][64]
                                                    const float* __restrict__ b2,
                                                    const int* __restrict__ batch,
                                                    float* __restrict__ out)
{
    __shared__ float sW[64 * 64];
    __shared__ float sH[16 * 64];
    __shared__ float sScale[64];
    __shared__ float sShift[64];
    const int tid = threadIdx.x;
    const int row0 = blockIdx.x * 16;

    if (tid < 64) {
        const float inv_n = 1.0f / (float)NN;
        const float mean = sums[tid] * inv_n;
        const float var = fmaxf(sumsq[tid] * inv_n - mean * mean, 0.f);
        const float sc = g1[tid] * rsqrtf(var + BN_EPS);
        sScale[tid] = sc;
        sShift[tid] = bt1[tid] - mean * sc;
    }
    for (int i = tid; i < 64 * 16; i += 256)
        ((float4*)sW)[i] = ((const float4*)W2)[i];
    __syncthreads();

    const float4* Zb = (const float4*)(Z + (size_t)row0 * 64);
    {
        const int i = tid;  // 256 float4s = 16 rows x 16
        const float4 z = Zb[i];
        const int c4 = i & 15;
        const float4 sc = ((const float4*)sScale)[c4];
        const float4 sh = ((const float4*)sShift)[c4];
        float4 h;
        h.x = fmaxf(fmaf(z.x, sc.x, sh.x), 0.f);
        h.y = fmaxf(fmaf(z.y, sc.y, sh.y), 0.f);
        h.z = fmaxf(fmaf(z.z, sc.z, sh.z), 0.f);
        h.w = fmaxf(fmaf(z.w, sc.w, sh.w), 0.f);
        ((float4*)sH)[i] = h;
    }
    __syncthreads();

    const int col = tid & 63;
    const int r0  = tid >> 6;
    const float bc = b2[col];
    float acc[4] = {bc, bc, bc, bc};
    for (int k = 0; k < 64; k += 4) {
        const float w0 = sW[(k + 0) * 64 + col];
        const float w1 = sW[(k + 1) * 64 + col];
        const float w2 = sW[(k + 2) * 64 + col];
        const float w3 = sW[(k + 3) * 64 + col];
#pragma unroll
        for (int rr = 0; rr < 4; ++rr) {
            const float4 hv = *(const float4*)&sH[(r0 + rr * 4) * 64 + k];
            acc[rr] = fmaf(hv.x, w0, acc[rr]);
            acc[rr] = fmaf(hv.y, w1, acc[rr]);
            acc[rr] = fmaf(hv.z, w2, acc[rr]);
            acc[rr] = fmaf(hv.w, w3, acc[rr]);
        }
    }
#pragma unroll
    for (int rr = 0; rr < 4; ++rr) {
        const int row = row0 + r0 + rr * 4;
        const float v = fmaxf(acc[rr], 0.f);
        if (POOL) {
            atomicAdd(&out[(size_t)batch[row] * 64 + col], v);
        } else {
            out[(size_t)row * 64 + col] = v;
        }
    }
}

// ---------------- final MLP: out = relu(P @ fW1 + fb1) @ fW2 + fb2 ----------------
__global__ __launch_bounds__(256) void final_mlp(const float* __restrict__ P,   // [512][64]
                                                 const float* __restrict__ W1,  // [64][64]
                                                 const float* __restrict__ b1,
                                                 const float* __restrict__ W2,  // [64][32]
                                                 const float* __restrict__ b2,
                                                 float* __restrict__ out)       // [512][32]
{
    __shared__ float sW1[64 * 64];
    __shared__ float sW2[64 * 32];
    __shared__ float sH[4 * 64];
    const int tid = threadIdx.x;
    const int row0 = blockIdx.x * 4;

    for (int i = tid; i < 1024; i += 256) ((float4*)sW1)[i] = ((const float4*)W1)[i];
    for (int i = tid; i < 512; i += 256) ((float4*)sW2)[i] = ((const float4*)W2)[i];
    __syncthreads();

    const int col = tid & 63;
    const int r = tid >> 6;
    float acc = b1[col];
    const float* prow = P + (size_t)(row0 + r) * 64;
    for (int k = 0; k < 64; ++k) acc = fmaf(prow[k], sW1[k * 64 + col], acc);
    sH[r * 64 + col] = fmaxf(acc, 0.f);
    __syncthreads();

    if (tid < 128) {
        const int c = tid & 31;
        const int r2 = tid >> 5;
        float a2 = b2[c];
        for (int k = 0; k < 64; ++k) a2 = fmaf(sH[r2 * 64 + k], sW2[k * 32 + c], a2);
        out[(size_t)(row0 + r2) * 32 + c] = a2;
    }
}

extern "C" void kernel_launch(void* const* d_in, const int* in_sizes, int n_in,
                              void* d_out, int out_size, void* d_ws, size_t ws_size,
                              hipStream_t stream)
{
    const float* x   = (const float*)d_in[0];
    const int* ei    = (const int*)d_in[1];   // [2][E]: first E = src, next E = dst
    const int* batch = (const int*)d_in[2];
    const float* cW1[3] = {(const float*)d_in[4],  (const float*)d_in[10], (const float*)d_in[16]};
    const float* cb1[3] = {(const float*)d_in[5],  (const float*)d_in[11], (const float*)d_in[17]};
    const float* cg1[3] = {(const float*)d_in[6],  (const float*)d_in[12], (const float*)d_in[18]};
    const float* cbt[3] = {(const float*)d_in[7],  (const float*)d_in[13], (const float*)d_in[19]};
    const float* cW2[3] = {(const float*)d_in[8],  (const float*)d_in[14], (const float*)d_in[20]};
    const float* cb2[3] = {(const float*)d_in[9],  (const float*)d_in[15], (const float*)d_in[21]};
    const float* fW1 = (const float*)d_in[22];
    const float* fb1 = (const float*)d_in[23];
    const float* fW2 = (const float*)d_in[24];
    const float* fb2 = (const float*)d_in[25];
    float* out = (float*)d_out;

    // workspace layout
    float* bufX     = (float*)d_ws;                        // N*64 fp32: X for layers>=1, Z (in-place safe)
    __half2* Qh     = (__half2*)(bufX + (size_t)NN * 64);  // (N+1)*32 half2 (row NN = zero row)
    float* pooled   = (float*)(Qh + (size_t)(NN + 1) * 32);// B*64
    float* statsbuf = pooled + (size_t)BB * 64;            // 3 layers x (64 sums + 64 sumsq)
    int* deg        = (int*)(statsbuf + 384);              // N
    int* poffs      = deg + NN;                            // N+1 (padded offsets)
    int* blockSums  = poffs + (NN + 1);                    // 256
    int* blockOff   = blockSums + 256;                     // 256
    uintptr_t pa = ((uintptr_t)(blockOff + 256) + 15) & ~(uintptr_t)15;
    unsigned short* srcPadded = (unsigned short*)pa;       // PADMAX (16B aligned)
    unsigned short* rank      = srcPadded + PADMAX;        // E

    const int* esrc = ei;
    const int* edst = ei + EE;

    const int gemm_blocks = NN / 16;   // 3125
    const int edge_blocks = EE / 256;  // 3125

    // ---- build padded CSR by dst ----
    hipMemsetAsync(deg, 0, NN * sizeof(int), stream);
    fill_kernel<<<(PADMAX / 2 + 255) / 256, 256, 0, stream>>>((unsigned int*)srcPadded);
    hist_rank_kernel<<<edge_blocks, 256, 0, stream>>>(edst, deg, rank);
    scanA_kernel<<<SCAN_BLOCKS, 256, 0, stream>>>(deg, poffs, blockSums);
    scanB_kernel<<<1, 256, 0, stream>>>(blockSums, blockOff, poffs);
    scanC_kernel<<<SCAN_BLOCKS, 256, 0, stream>>>(poffs, blockOff, statsbuf, pooled,
                                                  (unsigned int*)(Qh + (size_t)NN * 32));
    scatter_kernel<<<edge_blocks, 256, 0, stream>>>(esrc, edst, rank, poffs, srcPadded);

    for (int layer = 0; layer < 3; ++layer) {
        float* sums  = statsbuf + layer * 128;
        float* sumsq = sums + 64;

        // 1) projection Qh = half(x_cur @ W1)
        if (layer == 0)
            proj_kernel<DIN><<<gemm_blocks, 256, 0, stream>>>(x, cW1[0], Qh);
        else
            proj_kernel<HH><<<gemm_blocks, 256, 0, stream>>>(bufX, cW1[layer], Qh);

        // 2) gather-aggregate + fused BN stats (Z aliases bufX; gemm2 is row-local in-place)
        gather_kernel<<<GATHER_BLOCKS, 256, 0, stream>>>(Qh, poffs, srcPadded, cb1[layer],
                                                         bufX, sums, sumsq);

        // 3) BN finalize (in gemm2 prologue) + second linear + ReLU; last layer fuses pooling
        if (layer < 2) {
            gemm2_kernel<false><<<gemm_blocks, 256, 0, stream>>>(bufX, sums, sumsq, cg1[layer],
                                                                 cbt[layer], cW2[layer], cb2[layer],
                                                                 nullptr, bufX);
        } else {
            gemm2_kernel<true><<<gemm_blocks, 256, 0, stream>>>(bufX, sums, sumsq, cg1[layer],
                                                                cbt[layer], cW2[layer], cb2[layer],
                                                                batch, pooled);
        }
    }

    // final MLP on pooled graph features
    final_mlp<<<BB / 4, 256, 0, stream>>>(pooled, fW1, fb1, fW2, fb2, out);
}

// Round 8
// 350.923 us; speedup vs baseline: 1.0897x; 1.0403x over previous
//
#include <hip/hip_runtime.h>
#include <hip/hip_fp16.h>

#define NN 50000
#define EE 800000
#define BB 512
#define DIN 128
#define HH 64
#define DOUT 32
#define BN_EPS 1e-5f
#define SCAN_BLOCKS 196   // ceil(50000/256)
#define GATHER_BLOCKS 2048
#define PADMAX (16 * NN + EE + 64)   // worst-case padded CSR entries

// ---------------- proj: Qh = half(X @ W)  (layer 0 only) ----------------
template <int CIN>
__global__ __launch_bounds__(256) void proj_kernel(const float* __restrict__ X,
                                                   const float* __restrict__ W,  // [CIN][64]
                                                   __half2* __restrict__ Qh)     // [N+1][32]
{
    __shared__ float sW[CIN * 64];
    __shared__ float sX[16 * CIN];
    const int tid = threadIdx.x;
    const int row0 = blockIdx.x * 16;

    for (int i = tid; i < CIN * 16; i += 256)
        ((float4*)sW)[i] = ((const float4*)W)[i];
    const float* Xb = X + (size_t)row0 * CIN;
    for (int i = tid; i < 16 * CIN / 4; i += 256)
        ((float4*)sX)[i] = ((const float4*)Xb)[i];
    __syncthreads();

    const int col2 = tid & 31;   // column pair
    const int rg   = tid >> 5;   // 0..7 -> rows rg*2, rg*2+1
    float2 acc0 = {0.f, 0.f};
    float2 acc1 = {0.f, 0.f};
    const float* x0p = &sX[(rg * 2 + 0) * CIN];
    const float* x1p = &sX[(rg * 2 + 1) * CIN];
#pragma unroll 4
    for (int k = 0; k < CIN; ++k) {
        const float2 w = *(const float2*)&sW[k * 64 + col2 * 2];
        const float x0 = x0p[k];
        const float x1 = x1p[k];
        acc0.x = fmaf(x0, w.x, acc0.x);
        acc0.y = fmaf(x0, w.y, acc0.y);
        acc1.x = fmaf(x1, w.x, acc1.x);
        acc1.y = fmaf(x1, w.y, acc1.y);
    }
    const int r0 = row0 + rg * 2;
    Qh[(size_t)(r0 + 0) * 32 + col2] = __floats2half2_rn(acc0.x, acc0.y);
    Qh[(size_t)(r0 + 1) * 32 + col2] = __floats2half2_rn(acc1.x, acc1.y);
}

// ---------------- padded-CSR build ----------------
__global__ __launch_bounds__(256) void fill_kernel(unsigned int* __restrict__ dstw,
                                                   int* __restrict__ deg)
{
    const int i = blockIdx.x * 256 + threadIdx.x;
    if (i < PADMAX / 2) dstw[i] = 0xC350C350u;  // NN = 50000 = 0xC350 in both halves
    if (i < NN) deg[i] = 0;
}

__global__ __launch_bounds__(256) void hist_rank_kernel(const int* __restrict__ dst,
                                                        int* __restrict__ deg,
                                                        unsigned short* __restrict__ rank)
{
    const int e = blockIdx.x * 256 + threadIdx.x;  // exactly E threads
    rank[e] = (unsigned short)atomicAdd(&deg[dst[e]], 1);
}

// scan over padded capacities cap = max(16, roundup16(deg))
__global__ __launch_bounds__(256) void scanA_kernel(const int* __restrict__ deg,
                                                    int* __restrict__ poffs,
                                                    int* __restrict__ blockSums)
{
    __shared__ int s[256];
    const int t = threadIdx.x;
    const int i = blockIdx.x * 256 + t;
    int v = 0;
    if (i < NN) {
        const int d = deg[i];
        v = (d <= 16) ? 16 : ((d + 15) & ~15);
    }
    s[t] = v;
    __syncthreads();
    for (int off = 1; off < 256; off <<= 1) {
        const int a = (t >= off) ? s[t - off] : 0;
        __syncthreads();
        s[t] += a;
        __syncthreads();
    }
    if (i < NN) poffs[i] = s[t] - v;  // exclusive intra-block
    if (t == 255) blockSums[blockIdx.x] = s[255];
}

__global__ __launch_bounds__(256) void scanB_kernel(const int* __restrict__ blockSums,
                                                    int* __restrict__ blockOff,
                                                    int* __restrict__ poffs)
{
    __shared__ int s[256];
    const int t = threadIdx.x;
    const int v = (t < SCAN_BLOCKS) ? blockSums[t] : 0;
    s[t] = v;
    __syncthreads();
    for (int off = 1; off < 256; off <<= 1) {
        const int a = (t >= off) ? s[t - off] : 0;
        __syncthreads();
        s[t] += a;
        __syncthreads();
    }
    if (t < SCAN_BLOCKS) blockOff[t] = s[t] - v;  // exclusive
    if (t == SCAN_BLOCKS - 1) poffs[NN] = s[t];   // total padded size
}

__global__ __launch_bounds__(256) void scanC_kernel(int* __restrict__ poffs,
                                                    const int* __restrict__ blockOff,
                                                    float* __restrict__ statsbuf,  // 384 floats
                                                    float* __restrict__ pooled,    // B*64
                                                    unsigned int* __restrict__ qzero)  // Qh row NN
{
    const int i = blockIdx.x * 256 + threadIdx.x;
    if (i < NN) poffs[i] += blockOff[blockIdx.x];
    if (i < 384) statsbuf[i] = 0.f;
    if (i < BB * 64) pooled[i] = 0.f;
    if (blockIdx.x == 1 && threadIdx.x < 32) qzero[threadIdx.x] = 0u;
}

__global__ __launch_bounds__(256) void scatter_kernel(const int* __restrict__ src,
                                                      const int* __restrict__ dst,
                                                      const unsigned short* __restrict__ rank,
                                                      const int* __restrict__ poffs,
                                                      unsigned short* __restrict__ srcPadded)
{
    const int e = blockIdx.x * 256 + threadIdx.x;  // exactly E threads
    const int pos = poffs[dst[e]] + (int)rank[e];
    srcPadded[pos] = (unsigned short)src[e];
}

// ---------------- gather: Z[n] = Q[n] + b1 + sum_{src} Q[src]; fused BN column stats ----------------
// Column-parallel (lane c owns cols {2c,2c+1}; grp takes alternate edges), padded CSR (no masking),
// 2-node software pipeline: node i's row loads stay in flight while node i+1's poffs/idx/self
// loads are issued -> idx-fetch chain off the critical path.
__global__ __launch_bounds__(256) void gather_kernel(const __half2* __restrict__ Qh,
                                                     const int* __restrict__ poffs,
                                                     const unsigned short* __restrict__ srcPadded,
                                                     const float* __restrict__ b1,
                                                     float* __restrict__ Z,
                                                     float* __restrict__ sums,   // [64]
                                                     float* __restrict__ sumsq)  // [64]
{
    const int tid   = threadIdx.x;
    const int lane  = tid & 63;
    const int wid   = tid >> 6;       // wave in block: 0..3
    const int c     = lane & 31;      // column pair {2c, 2c+1}
    const int grp   = lane >> 5;      // 0/1: edge parity
    const int shamt = grp << 4;       // 0 or 16
    const uint* Qd  = (const uint*)Qh;   // 32 dwords per row
    const float2 bb = ((const float2*)b1)[c];

    float2 sa = {0.f, 0.f};
    float2 ta = {0.f, 0.f};
    const int step = GATHER_BLOCKS * 4;

    int node = blockIdx.x * 4 + wid;  // < 8192 < NN always
    // prefetch first node
    int p0 = poffs[node];
    int p1 = poffs[node + 1];
    uint4 ia = *(const uint4*)(srcPadded + p0);
    uint4 ib = *(const uint4*)(srcPadded + p0 + 8);
    bool two = (p1 - p0) > 16;
    uint4 ia2 = {0, 0, 0, 0}, ib2 = {0, 0, 0, 0};
    if (two) {
        ia2 = *(const uint4*)(srcPadded + p0 + 16);
        ib2 = *(const uint4*)(srcPadded + p0 + 24);
    }
    uint sr = Qd[(size_t)node * 32 + c];

    while (true) {
        // issue row loads for current node
        uint r[16];
#pragma unroll
        for (int k = 0; k < 4; ++k) {
            r[k]     = Qd[(size_t)(((&ia.x)[k] >> shamt) & 0xffffu) * 32 + c];
            r[4 + k] = Qd[(size_t)(((&ib.x)[k] >> shamt) & 0xffffu) * 32 + c];
        }
        if (two) {
#pragma unroll
            for (int k = 0; k < 4; ++k) {
                r[8 + k]  = Qd[(size_t)(((&ia2.x)[k] >> shamt) & 0xffffu) * 32 + c];
                r[12 + k] = Qd[(size_t)(((&ib2.x)[k] >> shamt) & 0xffffu) * 32 + c];
            }
        }

        // prefetch next node (overlaps with current row loads)
        const int nnode = node + step;
        const bool more = nnode < NN;
        int np0 = 0, np1 = 0;
        uint4 nia = {0, 0, 0, 0}, nib = {0, 0, 0, 0};
        uint4 nia2 = {0, 0, 0, 0}, nib2 = {0, 0, 0, 0};
        uint nsr = 0;
        bool ntwo = false;
        if (more) {
            np0 = poffs[nnode];
            np1 = poffs[nnode + 1];
            nia = *(const uint4*)(srcPadded + np0);
            nib = *(const uint4*)(srcPadded + np0 + 8);
            ntwo = (np1 - np0) > 16;
            if (ntwo) {
                nia2 = *(const uint4*)(srcPadded + np0 + 16);
                nib2 = *(const uint4*)(srcPadded + np0 + 24);
            }
            nsr = Qd[(size_t)nnode * 32 + c];
        }

        // accumulate current node
        float2 acc = {0.f, 0.f};
#pragma unroll
        for (int k = 0; k < 8; ++k) {
            const float2 p = __half22float2(*(const __half2*)&r[k]);
            acc.x += p.x;
            acc.y += p.y;
        }
        if (two) {
#pragma unroll
            for (int k = 8; k < 16; ++k) {
                const float2 p = __half22float2(*(const __half2*)&r[k]);
                acc.x += p.x;
                acc.y += p.y;
            }
        }
        // rare: degree > 32
        for (int j = p0 + 32; j < p1; j += 16) {
            const uint4 ja = *(const uint4*)(srcPadded + j);
            const uint4 jb = *(const uint4*)(srcPadded + j + 8);
            uint rr[8];
#pragma unroll
            for (int k = 0; k < 4; ++k) {
                rr[k]     = Qd[(size_t)(((&ja.x)[k] >> shamt) & 0xffffu) * 32 + c];
                rr[4 + k] = Qd[(size_t)(((&jb.x)[k] >> shamt) & 0xffffu) * 32 + c];
            }
#pragma unroll
            for (int k = 0; k < 8; ++k) {
                const float2 p = __half22float2(*(const __half2*)&rr[k]);
                acc.x += p.x;
                acc.y += p.y;
            }
        }

        // combine the two edge-parity groups
        acc.x += __shfl_xor(acc.x, 32);
        acc.y += __shfl_xor(acc.y, 32);

        if (grp == 0) {
            const float2 p = __half22float2(*(const __half2*)&sr);
            acc.x += p.x + bb.x;
            acc.y += p.y + bb.y;
            ((float2*)Z)[(size_t)node * 32 + c] = acc;
            sa.x += acc.x; sa.y += acc.y;
            ta.x += acc.x * acc.x; ta.y += acc.y * acc.y;
        }

        if (!more) break;
        node = nnode; p0 = np0; p1 = np1;
        ia = nia; ib = nib; two = ntwo;
        if (two) { ia2 = nia2; ib2 = nib2; }
        sr = nsr;
    }

    // block-level stats reduce: 4 waves x 32 lanes x 4 values -> 128 atomics
    __shared__ float red[4][32][4];
    if (grp == 0) {
        float* rp = red[wid][c];
        rp[0] = sa.x; rp[1] = sa.y; rp[2] = ta.x; rp[3] = ta.y;
    }
    __syncthreads();
    if (tid < 128) {
        const int c2 = tid >> 2;   // 0..31
        const int k  = tid & 3;    // 0..3
        const float v = red[0][c2][k] + red[1][c2][k] + red[2][c2][k] + red[3][c2][k];
        float* dstp;
        if (k == 0)      dstp = &sums[2 * c2 + 0];
        else if (k == 1) dstp = &sums[2 * c2 + 1];
        else if (k == 2) dstp = &sumsq[2 * c2 + 0];
        else             dstp = &sumsq[2 * c2 + 1];
        atomicAdd(dstp, v);
    }
}

// ---------------- fused: Qh_next = half( relu( relu(BN(Z)) @ W2 + b2 ) @ W1next ) ----------------
__global__ __launch_bounds__(256) void gemm2proj_kernel(const float* __restrict__ Z,
                                                        const float* __restrict__ sums,
                                                        const float* __restrict__ sumsq,
                                                        const float* __restrict__ g1,
                                                        const float* __restrict__ bt1,
                                                        const float* __restrict__ W2,   // [64][64]
                                                        const float* __restrict__ b2,
                                                        const float* __restrict__ W1n,  // [64][64]
                                                        __half2* __restrict__ QhOut)    // [N+1][32]
{
    __shared__ float sW2[64 * 64];
    __shared__ float sW1[64 * 64];
    __shared__ float sH[16 * 64];
    __shared__ float sA[16 * 64];
    __shared__ float sScale[64];
    __shared__ float sShift[64];
    const int tid = threadIdx.x;
    const int row0 = blockIdx.x * 16;

    if (tid < 64) {
        const float inv_n = 1.0f / (float)NN;
        const float mean = sums[tid] * inv_n;
        const float var = fmaxf(sumsq[tid] * inv_n - mean * mean, 0.f);
        const float sc = g1[tid] * rsqrtf(var + BN_EPS);
        sScale[tid] = sc;
        sShift[tid] = bt1[tid] - mean * sc;
    }
    for (int i = tid; i < 1024; i += 256) {
        ((float4*)sW2)[i] = ((const float4*)W2)[i];
        ((float4*)sW1)[i] = ((const float4*)W1n)[i];
    }
    __syncthreads();

    const float4* Zb = (const float4*)(Z + (size_t)row0 * 64);
    {
        const int i = tid;  // 256 float4s = 16 rows x 16
        const float4 z = Zb[i];
        const int c4 = i & 15;
        const float4 sc = ((const float4*)sScale)[c4];
        const float4 sh = ((const float4*)sShift)[c4];
        float4 h;
        h.x = fmaxf(fmaf(z.x, sc.x, sh.x), 0.f);
        h.y = fmaxf(fmaf(z.y, sc.y, sh.y), 0.f);
        h.z = fmaxf(fmaf(z.z, sc.z, sh.z), 0.f);
        h.w = fmaxf(fmaf(z.w, sc.w, sh.w), 0.f);
        ((float4*)sH)[i] = h;
    }
    __syncthreads();

    // A = relu(H @ W2 + b2) -> sA
    {
        const int col = tid & 63;
        const int r0  = tid >> 6;
        const float bc = b2[col];
        float acc[4] = {bc, bc, bc, bc};
        for (int k = 0; k < 64; k += 4) {
            const float w0 = sW2[(k + 0) * 64 + col];
            const float w1 = sW2[(k + 1) * 64 + col];
            const float w2 = sW2[(k + 2) * 64 + col];
            const float w3 = sW2[(k + 3) * 64 + col];
#pragma unroll
            for (int rr = 0; rr < 4; ++rr) {
                const float4 hv = *(const float4*)&sH[(r0 + rr * 4) * 64 + k];
                acc[rr] = fmaf(hv.x, w0, acc[rr]);
                acc[rr] = fmaf(hv.y, w1, acc[rr]);
                acc[rr] = fmaf(hv.z, w2, acc[rr]);
                acc[rr] = fmaf(hv.w, w3, acc[rr]);
            }
        }
#pragma unroll
        for (int rr = 0; rr < 4; ++rr)
            sA[(r0 + rr * 4) * 64 + col] = fmaxf(acc[rr], 0.f);
    }
    __syncthreads();

    // Qh = half(A @ W1n)
    {
        const int col2 = tid & 31;   // column pair
        const int rg   = tid >> 5;   // 0..7 -> rows rg*2, rg*2+1
        float2 acc0 = {0.f, 0.f};
        float2 acc1 = {0.f, 0.f};
        const float* a0p = &sA[(rg * 2 + 0) * 64];
        const float* a1p = &sA[(rg * 2 + 1) * 64];
#pragma unroll 4
        for (int k = 0; k < 64; ++k) {
            const float2 w = *(const float2*)&sW1[k * 64 + col2 * 2];
            const float a0 = a0p[k];
            const float a1 = a1p[k];
            acc0.x = fmaf(a0, w.x, acc0.x);
            acc0.y = fmaf(a0, w.y, acc0.y);
            acc1.x = fmaf(a1, w.x, acc1.x);
            acc1.y = fmaf(a1, w.y, acc1.y);
        }
        const int r0 = row0 + rg * 2;
        QhOut[(size_t)(r0 + 0) * 32 + col2] = __floats2half2_rn(acc0.x, acc0.y);
        QhOut[(size_t)(r0 + 1) * 32 + col2] = __floats2half2_rn(acc1.x, acc1.y);
    }
}

// ---------------- gemm2 (pool epilogue, last layer) ----------------
__global__ __launch_bounds__(256) void gemm2pool_kernel(const float* __restrict__ Z,
                                                        const float* __restrict__ sums,
                                                        const float* __restrict__ sumsq,
                                                        const float* __restrict__ g1,
                                                        const float* __restrict__ bt1,
                                                        const float* __restrict__ W2,  // [64][64]
                                                        const float* __restrict__ b2,
                                                        const int* __restrict__ batch,
                                                        float* __restrict__ out)       // pooled [B][64]
{
    __shared__ float sW[64 * 64];
    __shared__ float sH[16 * 64];
    __shared__ float sScale[64];
    __shared__ float sShift[64];
    const int tid = threadIdx.x;
    const int row0 = blockIdx.x * 16;

    if (tid < 64) {
        const float inv_n = 1.0f / (float)NN;
        const float mean = sums[tid] * inv_n;
        const float var = fmaxf(sumsq[tid] * inv_n - mean * mean, 0.f);
        const float sc = g1[tid] * rsqrtf(var + BN_EPS);
        sScale[tid] = sc;
        sShift[tid] = bt1[tid] - mean * sc;
    }
    for (int i = tid; i < 1024; i += 256)
        ((float4*)sW)[i] = ((const float4*)W2)[i];
    __syncthreads();

    const float4* Zb = (const float4*)(Z + (size_t)row0 * 64);
    {
        const int i = tid;
        const float4 z = Zb[i];
        const int c4 = i & 15;
        const float4 sc = ((const float4*)sScale)[c4];
        const float4 sh = ((const float4*)sShift)[c4];
        float4 h;
        h.x = fmaxf(fmaf(z.x, sc.x, sh.x), 0.f);
        h.y = fmaxf(fmaf(z.y, sc.y, sh.y), 0.f);
        h.z = fmaxf(fmaf(z.z, sc.z, sh.z), 0.f);
        h.w = fmaxf(fmaf(z.w, sc.w, sh.w), 0.f);
        ((float4*)sH)[i] = h;
    }
    __syncthreads();

    const int col = tid & 63;
    const int r0  = tid >> 6;
    const float bc = b2[col];
    float acc[4] = {bc, bc, bc, bc};
    for (int k = 0; k < 64; k += 4) {
        const float w0 = sW[(k + 0) * 64 + col];
        const float w1 = sW[(k + 1) * 64 + col];
        const float w2 = sW[(k + 2) * 64 + col];
        const float w3 = sW[(k + 3) * 64 + col];
#pragma unroll
        for (int rr = 0; rr < 4; ++rr) {
            const float4 hv = *(const float4*)&sH[(r0 + rr * 4) * 64 + k];
            acc[rr] = fmaf(hv.x, w0, acc[rr]);
            acc[rr] = fmaf(hv.y, w1, acc[rr]);
            acc[rr] = fmaf(hv.z, w2, acc[rr]);
            acc[rr] = fmaf(hv.w, w3, acc[rr]);
        }
    }
#pragma unroll
    for (int rr = 0; rr < 4; ++rr) {
        const int row = row0 + r0 + rr * 4;
        const float v = fmaxf(acc[rr], 0.f);
        atomicAdd(&out[(size_t)batch[row] * 64 + col], v);
    }
}

// ---------------- final MLP: out = relu(P @ fW1 + fb1) @ fW2 + fb2 ----------------
__global__ __launch_bounds__(256) void final_mlp(const float* __restrict__ P,   // [512][64]
                                                 const float* __restrict__ W1,  // [64][64]
                                                 const float* __restrict__ b1,
                                                 const float* __restrict__ W2,  // [64][32]
                                                 const float* __restrict__ b2,
                                                 float* __restrict__ out)       // [512][32]
{
    __shared__ float sW1[64 * 64];
    __shared__ float sW2[64 * 32];
    __shared__ float sH[4 * 64];
    const int tid = threadIdx.x;
    const int row0 = blockIdx.x * 4;

    for (int i = tid; i < 1024; i += 256) ((float4*)sW1)[i] = ((const float4*)W1)[i];
    for (int i = tid; i < 512; i += 256) ((float4*)sW2)[i] = ((const float4*)W2)[i];
    __syncthreads();

    const int col = tid & 63;
    const int r = tid >> 6;
    float acc = b1[col];
    const float* prow = P + (size_t)(row0 + r) * 64;
    for (int k = 0; k < 64; ++k) acc = fmaf(prow[k], sW1[k * 64 + col], acc);
    sH[r * 64 + col] = fmaxf(acc, 0.f);
    __syncthreads();

    if (tid < 128) {
        const int c = tid & 31;
        const int r2 = tid >> 5;
        float a2 = b2[c];
        for (int k = 0; k < 64; ++k) a2 = fmaf(sH[r2 * 64 + k], sW2[k * 32 + c], a2);
        out[(size_t)(row0 + r2) * 32 + c] = a2;
    }
}

extern "C" void kernel_launch(void* const* d_in, const int* in_sizes, int n_in,
                              void* d_out, int out_size, void* d_ws, size_t ws_size,
                              hipStream_t stream)
{
    const float* x   = (const float*)d_in[0];
    const int* ei    = (const int*)d_in[1];   // [2][E]: first E = src, next E = dst
    const int* batch = (const int*)d_in[2];
    const float* cW1[3] = {(const float*)d_in[4],  (const float*)d_in[10], (const float*)d_in[16]};
    const float* cb1[3] = {(const float*)d_in[5],  (const float*)d_in[11], (const float*)d_in[17]};
    const float* cg1[3] = {(const float*)d_in[6],  (const float*)d_in[12], (const float*)d_in[18]};
    const float* cbt[3] = {(const float*)d_in[7],  (const float*)d_in[13], (const float*)d_in[19]};
    const float* cW2[3] = {(const float*)d_in[8],  (const float*)d_in[14], (const float*)d_in[20]};
    const float* cb2[3] = {(const float*)d_in[9],  (const float*)d_in[15], (const float*)d_in[21]};
    const float* fW1 = (const float*)d_in[22];
    const float* fb1 = (const float*)d_in[23];
    const float* fW2 = (const float*)d_in[24];
    const float* fb2 = (const float*)d_in[25];
    float* out = (float*)d_out;

    // workspace layout
    float* bufX     = (float*)d_ws;                        // N*64 fp32: Z buffer
    __half2* Qh     = (__half2*)(bufX + (size_t)NN * 64);  // (N+1)*32 half2 (row NN = zero row)
    float* pooled   = (float*)(Qh + (size_t)(NN + 1) * 32);// B*64
    float* statsbuf = pooled + (size_t)BB * 64;            // 3 layers x (64 sums + 64 sumsq)
    int* deg        = (int*)(statsbuf + 384);              // N
    int* poffs      = deg + NN;                            // N+1 (padded offsets)
    int* blockSums  = poffs + (NN + 1);                    // 256
    int* blockOff   = blockSums + 256;                     // 256
    uintptr_t pa = ((uintptr_t)(blockOff + 256) + 15) & ~(uintptr_t)15;
    unsigned short* srcPadded = (unsigned short*)pa;       // PADMAX (16B aligned)
    unsigned short* rank      = srcPadded + PADMAX;        // E

    const int* esrc = ei;
    const int* edst = ei + EE;

    const int gemm_blocks = NN / 16;   // 3125
    const int edge_blocks = EE / 256;  // 3125

    // ---- build padded CSR by dst ----
    fill_kernel<<<(PADMAX / 2 + 255) / 256, 256, 0, stream>>>((unsigned int*)srcPadded, deg);
    hist_rank_kernel<<<edge_blocks, 256, 0, stream>>>(edst, deg, rank);
    scanA_kernel<<<SCAN_BLOCKS, 256, 0, stream>>>(deg, poffs, blockSums);
    scanB_kernel<<<1, 256, 0, stream>>>(blockSums, blockOff, poffs);
    scanC_kernel<<<SCAN_BLOCKS, 256, 0, stream>>>(poffs, blockOff, statsbuf, pooled,
                                                  (unsigned int*)(Qh + (size_t)NN * 32));
    scatter_kernel<<<edge_blocks, 256, 0, stream>>>(esrc, edst, rank, poffs, srcPadded);

    // layer 0 projection
    proj_kernel<DIN><<<gemm_blocks, 256, 0, stream>>>(x, cW1[0], Qh);

    for (int layer = 0; layer < 3; ++layer) {
        float* sums  = statsbuf + layer * 128;
        float* sumsq = sums + 64;

        // gather-aggregate + fused BN stats
        gather_kernel<<<GATHER_BLOCKS, 256, 0, stream>>>(Qh, poffs, srcPadded, cb1[layer],
                                                         bufX, sums, sumsq);

        if (layer < 2) {
            // BN + gemm2 + ReLU + next-layer proj, fused -> Qh
            gemm2proj_kernel<<<gemm_blocks, 256, 0, stream>>>(bufX, sums, sumsq, cg1[layer],
                                                              cbt[layer], cW2[layer], cb2[layer],
                                                              cW1[layer + 1], Qh);
        } else {
            gemm2pool_kernel<<<gemm_blocks, 256, 0, stream>>>(bufX, sums, sumsq, cg1[layer],
                                                              cbt[layer], cW2[layer], cb2[layer],
                                                              batch, pooled);
        }
    }

    // final MLP on pooled graph features
    final_mlp<<<BB / 4, 256, 0, stream>>>(pooled, fW1, fb1, fW2, fb2, out);
}